// Round 5
// baseline (118.292 us; speedup 1.0000x reference)
//
#include <hip/hip_runtime.h>
#include <hip/hip_bf16.h>
#include <stdint.h>

// ---------------------------------------------------------------------------
// SupervisedContrastiveLoss, B=4096, D=1024, C=32, T=0.1, eps=1e-8
// out = (1/B) * [ sum_i (log(denom_i)*W_i - posS_i) - pw*INV_T*||G||_F^2 ]
// R5: scl_main gemm K-loop restructured: LDS double-buffer, ONE barrier/kt,
//     prefetch issued post-barrier (latency overlapped with compute).
//     G-blocks use cvt_pk_f32_fp8 + packed f32x2 FMA (half the VALU).
// ---------------------------------------------------------------------------

typedef float f32x4 __attribute__((ext_vector_type(4)));
typedef float f32x2 __attribute__((ext_vector_type(2)));
typedef long i64;

#define INV_T 10.0f
#define Z_SCALE (INV_T / 256.0f)   // both fp8 operands carry x16

#define GLD16(gp, lp)                                                          \
    __builtin_amdgcn_global_load_lds(                                          \
        (const __attribute__((address_space(1))) uint32_t*)(gp),               \
        (__attribute__((address_space(3))) uint32_t*)(lp), 16, 0, 0)

// workspace layout (bytes)
#define OFF_RNF8  0                         // 4096*1024 = 4194304
#define OFF_DENOM 4194304                   // 4096*4
#define OFF_POSS  (OFF_DENOM + 16384)
#define OFF_G     (OFF_POSS + 16384)        // 1024*32*4 = 131072
#define OFF_OACC  (OFF_G + 131072)          // double
#define OFF_DONE  (OFF_OACC + 16)           // int
#define ZERO_SPAN 167936                    // 41*4096 >= 163904 (zeroed region)
#define OFF_CSP   (OFF_DENOM + ZERO_SPAN)   // 32*32*4 colsum partials
#define OFF_CCP   (OFF_CSP + 4096)          // 32*32*4 histogram partials
#define OFF_W     (OFF_CCP + 4096)          // 4096*4

// ---------------- D1: normalize -> fp8(x16) | prep partials | zero ----------
__global__ __launch_bounds__(256) void scl_stage1(const float* __restrict__ rep,
                                                  const float* __restrict__ sl,
                                                  const int* __restrict__ labels,
                                                  uint32_t* __restrict__ rnf8,
                                                  float* __restrict__ cs_part,
                                                  int* __restrict__ cc_part,
                                                  char* __restrict__ zbase) {
    int b = blockIdx.x;
    int t = threadIdx.x;
    if (b < 4096) {
        int row = b;
        const float4* src = reinterpret_cast<const float4*>(rep + (size_t)row * 1024);
        float4 v = src[t];
        float s = v.x * v.x + v.y * v.y + v.z * v.z + v.w * v.w;
#pragma unroll
        for (int m = 1; m < 64; m <<= 1) s += __shfl_xor(s, m, 64);
        __shared__ float red[4];
        if ((t & 63) == 0) red[t >> 6] = s;
        __syncthreads();
        s = red[0] + red[1] + red[2] + red[3];
        float nf = 16.0f / fmaxf(sqrtf(s), 1e-8f);   // x16 into fp8 normal range
        int p = 0;
        p = __builtin_amdgcn_cvt_pk_fp8_f32(v.x * nf, v.y * nf, p, false);
        p = __builtin_amdgcn_cvt_pk_fp8_f32(v.z * nf, v.w * nf, p, true);
        rnf8[row * 256 + t] = (uint32_t)p;
    } else if (b < 4128) {
        // prep partials: colsum of soft_labels + class histogram (128 rows/slab)
        __shared__ float part[8][32];
        __shared__ int bins[32];
        int bb = b - 4096;
        if (t < 32) bins[t] = 0;
        __syncthreads();
        if (t < 128) atomicAdd(&bins[labels[bb * 128 + t]], 1);
        int c = t & 31, rg = t >> 5;
        float s = 0.f;
#pragma unroll 4
        for (int k = 0; k < 16; ++k) {
            int i = bb * 128 + rg * 16 + k;
            s += sl[i * 32 + c];
        }
        part[rg][c] = s;
        __syncthreads();
        if (t < 32) {
            float tot = 0.f;
#pragma unroll
            for (int g = 0; g < 8; ++g) tot += part[g][t];
            cs_part[bb * 32 + t] = tot;
            cc_part[bb * 32 + t] = bins[t];
        }
    } else {
        // zero blocks: denom/posS/G/oacc/done (consumed in D2/D3)
        int zb = b - 4128;
        *(uint4*)(zbase + (size_t)zb * 4096 + t * 16) = (uint4){0, 0, 0, 0};
    }
}

// ---------------- D2: fused gemm + G + W ------------------------------------
__global__ __launch_bounds__(256) void scl_main(const uint8_t* __restrict__ rnf8,
                                                const float* __restrict__ sl,
                                                const int* __restrict__ labels,
                                                const float* __restrict__ cs_part,
                                                const int* __restrict__ cc_part,
                                                const int* __restrict__ pwp,
                                                float* __restrict__ denom,
                                                float* __restrict__ posS,
                                                float* __restrict__ G,
                                                float* __restrict__ W) {
    int tid = threadIdx.x;

    if (blockIdx.x >= 528) {
        if (blockIdx.x < 1040) {
            // ---- G = rn^T @ SL : 16 d-blocks x 32 k-splits ----
            int idx = blockIdx.x - 528;
            int dblk = idx & 15, ks = idx >> 4;
            int dq = tid >> 5, c = tid & 31;
            int d0 = dblk * 64 + dq * 8;
            f32x2 acc2[4];
#pragma unroll
            for (int j = 0; j < 4; ++j) acc2[j] = (f32x2){0.f, 0.f};
            int i0 = ks * 128;
#pragma unroll 4
            for (int k = 0; k < 128; ++k) {
                int i = i0 + k;
                uint2 rv = *(const uint2*)&rnf8[(size_t)i * 1024 + d0];
                float sv = sl[i * 32 + c];
                f32x2 sv2 = {sv, sv};
                acc2[0] += __builtin_amdgcn_cvt_pk_f32_fp8((int)rv.x, false) * sv2;
                acc2[1] += __builtin_amdgcn_cvt_pk_f32_fp8((int)rv.x, true) * sv2;
                acc2[2] += __builtin_amdgcn_cvt_pk_f32_fp8((int)rv.y, false) * sv2;
                acc2[3] += __builtin_amdgcn_cvt_pk_f32_fp8((int)rv.y, true) * sv2;
            }
#pragma unroll
            for (int j = 0; j < 4; ++j) {
                atomicAdd(&G[(d0 + 2 * j) * 32 + c], acc2[j][0] * 0.0625f);
                atomicAdd(&G[(d0 + 2 * j + 1) * 32 + c], acc2[j][1] * 0.0625f);
            }
        } else {
            // ---- W[i] = (ccnt[l_i]-1) + pw*(sl_i . csum) : 16 blocks x 256 rows
            __shared__ __align__(16) float css[32];
            __shared__ int ccs[32];
            if (tid < 32) {
                float s = 0.f; int n = 0;
#pragma unroll
                for (int b = 0; b < 32; ++b) { s += cs_part[b * 32 + tid]; n += cc_part[b * 32 + tid]; }
                css[tid] = s; ccs[tid] = n;
            }
            __syncthreads();
            int bits = *pwp;
            float pw = (bits >= -(1 << 22) && bits <= (1 << 22)) ? (float)bits
                                                                 : __int_as_float(bits);
            int i = (blockIdx.x - 1040) * 256 + tid;
            const f32x4* sl4 = (const f32x4*)sl;
            const f32x4* cs4 = (const f32x4*)css;
            float dW = 0.f;
#pragma unroll
            for (int q = 0; q < 8; ++q) {
                f32x4 s = sl4[i * 8 + q];
                f32x4 c = cs4[q];
                dW += s[0] * c[0] + s[1] * c[1] + s[2] * c[2] + s[3] * c[3];
            }
            W[i] = (float)(ccs[labels[i]] - 1) + pw * dW;
        }
        return;
    }

    // ---- main fp8 GEMM tile: rowsum/colsum of exp(Z), pos*Z ----
    // double-buffered LDS, one barrier per kt, post-barrier prefetch
    __shared__ __align__(16) uint8_t As[2 * 128 * 64];
    __shared__ __align__(16) uint8_t Bs[2 * 128 * 64];
    __shared__ int lblA[128], lblB[128];

    int L = blockIdx.x;
    int bi = 0, rem = L;
    while (rem >= 32 - bi) { rem -= 32 - bi; ++bi; }
    int bj = bi + rem;
    int rowA0 = bi * 128, colB0 = bj * 128;

    if (tid < 128) {
        lblA[tid] = labels[rowA0 + tid];
        lblB[tid] = labels[colB0 + tid];
    }

    int lane = tid & 63, warp = tid >> 6;
    int wr = warp >> 1, wc = warp & 1;
    int m_ = lane & 15, g = lane >> 4;

    // staging: lane l -> row l>>2, LDS slot l&3; fetch global chunk (l&3)^((l>>3)&3)
    int r4 = lane >> 2;
    int csw = (lane & 3) ^ ((lane >> 3) & 3);
    const uint8_t* gA0 = rnf8 + (size_t)(rowA0 + warp * 32 + r4) * 1024 + csw * 16;
    const uint8_t* gB0 = rnf8 + (size_t)(colB0 + warp * 32 + r4) * 1024 + csw * 16;

    f32x4 acc[4][4];
#pragma unroll
    for (int a = 0; a < 4; ++a)
#pragma unroll
        for (int b = 0; b < 4; ++b) acc[a][b] = (f32x4){0.f, 0.f, 0.f, 0.f};

    // frag LDS offset: global 16B-chunk q of row r lives at slot q^((r>>1)&3)
    int fsw = (g ^ ((m_ >> 1) & 3)) * 16;

    // prologue: stage kt=0 into buffer 0
    GLD16(gA0,         &As[(warp * 32) * 64]);
    GLD16(gA0 + 16384, &As[(warp * 32 + 16) * 64]);
    GLD16(gB0,         &Bs[(warp * 32) * 64]);
    GLD16(gB0 + 16384, &Bs[(warp * 32 + 16) * 64]);

    for (int kt = 0; kt < 16; ++kt) {
        __syncthreads();  // drains vmcnt(0): buf[kt&1] loads (in flight ~1 full kt) done
        int cb = (kt & 1) * 8192, nb = 8192 - cb;
        if (kt < 15) {
            // prefetch kt+1 into the other buffer (safe: last read at kt-1, sealed above)
            GLD16(gA0 + (kt + 1) * 64,         &As[nb + (warp * 32) * 64]);
            GLD16(gA0 + (kt + 1) * 64 + 16384, &As[nb + (warp * 32 + 16) * 64]);
            GLD16(gB0 + (kt + 1) * 64,         &Bs[nb + (warp * 32) * 64]);
            GLD16(gB0 + (kt + 1) * 64 + 16384, &Bs[nb + (warp * 32 + 16) * 64]);
        }
        // one b128 per tile: k-permuted pair of fp8 frags (s=0: bytes 0-7, s=1: 8-15)
        f32x4 aq[4], bq[4];
#pragma unroll
        for (int ti = 0; ti < 4; ++ti) {
            int rowLoc = wr * 64 + ti * 16 + m_;
            aq[ti] = *(const f32x4*)&As[cb + rowLoc * 64 + fsw];
        }
#pragma unroll
        for (int tj = 0; tj < 4; ++tj) {
            int colLoc = wc * 64 + tj * 16 + m_;
            bq[tj] = *(const f32x4*)&Bs[cb + colLoc * 64 + fsw];
        }
#pragma unroll
        for (int s = 0; s < 2; ++s)
#pragma unroll
            for (int ti = 0; ti < 4; ++ti)
#pragma unroll
                for (int tj = 0; tj < 4; ++tj) {
                    i64 a = ((const i64*)&aq[ti])[s];
                    i64 b = ((const i64*)&bq[tj])[s];
                    acc[ti][tj] = __builtin_amdgcn_mfma_f32_16x16x32_fp8_fp8(
                        a, b, acc[ti][tj], 0, 0, 0);
                }
    }

    // epilogue: C layout col=lane&15, row=(lane>>4)*4+reg
    bool isDiag = (bi == bj);
    int cl = m_;
    float colE[4] = {0.f, 0.f, 0.f, 0.f}, colP[4] = {0.f, 0.f, 0.f, 0.f};
#pragma unroll
    for (int ti = 0; ti < 4; ++ti) {
        int rowLoc = wr * 64 + ti * 16 + g * 4;
        float rE[4] = {0.f, 0.f, 0.f, 0.f}, rP[4] = {0.f, 0.f, 0.f, 0.f};
        int lr[4];
#pragma unroll
        for (int r = 0; r < 4; ++r) lr[r] = lblA[rowLoc + r];
#pragma unroll
        for (int tj = 0; tj < 4; ++tj) {
            int colLoc = wc * 64 + tj * 16 + cl;
            int gCol = colB0 + colLoc;
            int lc = lblB[colLoc];
            f32x4 a = acc[ti][tj];
#pragma unroll
            for (int r = 0; r < 4; ++r) {
                int gRow = rowA0 + rowLoc + r;
                float z = Z_SCALE * a[r];
                float e = __expf(z);
                bool offd = (gRow != gCol);
                if (!offd) e = 0.f;
                rE[r] += e;
                colE[tj] += e;
                if (offd && (lr[r] == lc)) { rP[r] += z; colP[tj] += z; }
            }
        }
#pragma unroll
        for (int r = 0; r < 4; ++r) {
            float v = rE[r], p = rP[r];
#pragma unroll
            for (int msk = 1; msk < 16; msk <<= 1) {
                v += __shfl_xor(v, msk, 64);
                p += __shfl_xor(p, msk, 64);
            }
            if (cl == 0) {
                int gRow = rowA0 + rowLoc + r;
                atomicAdd(&denom[gRow], v);
                atomicAdd(&posS[gRow], p);
            }
        }
    }
    if (!isDiag) {
#pragma unroll
        for (int tj = 0; tj < 4; ++tj) {
            float v = colE[tj], p = colP[tj];
            v += __shfl_xor(v, 16, 64); p += __shfl_xor(p, 16, 64);
            v += __shfl_xor(v, 32, 64); p += __shfl_xor(p, 32, 64);
            if (g == 0) {
                int gCol = colB0 + wc * 64 + tj * 16 + cl;
                atomicAdd(&denom[gCol], v);
                atomicAdd(&posS[gCol], p);
            }
        }
    }
}

// ---------------- D3: finalize (8 row-blocks + 1 G-block), done-counter -----
__global__ __launch_bounds__(256) void scl_finalize(const float* __restrict__ denom,
                                                    const float* __restrict__ posS,
                                                    const float* __restrict__ W,
                                                    const float* __restrict__ G,
                                                    const int* __restrict__ pwp,
                                                    double* __restrict__ oacc,
                                                    int* __restrict__ done,
                                                    float* __restrict__ out) {
    int t = threadIdx.x;
    __shared__ double wsum[4];
    double contrib = 0.0;

    if (blockIdx.x < 8) {
        int i0 = blockIdx.x * 512 + t;
        float t0 = __logf(denom[i0]) * W[i0] - posS[i0];
        float t1 = __logf(denom[i0 + 256]) * W[i0 + 256] - posS[i0 + 256];
        double td = (double)t0 + (double)t1;
#pragma unroll
        for (int m = 1; m < 64; m <<= 1) td += __shfl_xor(td, m, 64);
        if ((t & 63) == 0) wsum[t >> 6] = td;
        __syncthreads();
        contrib = wsum[0] + wsum[1] + wsum[2] + wsum[3];
    } else {
        int bits = *pwp;
        float pw = (bits >= -(1 << 22) && bits <= (1 << 22)) ? (float)bits
                                                             : __int_as_float(bits);
        const f32x4* G4 = (const f32x4*)G;
        float gs = 0.f;
#pragma unroll
        for (int q = 0; q < 32; ++q) {
            f32x4 v = G4[q * 256 + t];
            gs += v[0] * v[0] + v[1] * v[1] + v[2] * v[2] + v[3] * v[3];
        }
        double gd = (double)gs;
#pragma unroll
        for (int m = 1; m < 64; m <<= 1) gd += __shfl_xor(gd, m, 64);
        if ((t & 63) == 0) wsum[t >> 6] = gd;
        __syncthreads();
        contrib = -(double)(pw * INV_T) * (wsum[0] + wsum[1] + wsum[2] + wsum[3]);
    }

    if (t == 0) {
        atomicAdd(oacc, contrib);
        __threadfence();
        int old = atomicAdd(done, 1);
        if (old == 8) {  // last of 9 blocks
            double tot = atomicAdd(oacc, 0.0);  // coherent read
            out[0] = (float)(tot * (1.0 / 4096.0));
        }
    }
}

// ---------------------------------------------------------------------------
extern "C" void kernel_launch(void* const* d_in, const int* in_sizes, int n_in,
                              void* d_out, int out_size, void* d_ws, size_t ws_size,
                              hipStream_t stream) {
    const float* rep = (const float*)d_in[0];
    const float* sl = (const float*)d_in[1];
    const int* labels = (const int*)d_in[2];
    const int* pwp = (const int*)d_in[3];

    char* ws = (char*)d_ws;
    uint8_t* rnf8 = (uint8_t*)(ws + OFF_RNF8);
    float* denom = (float*)(ws + OFF_DENOM);
    float* posS = (float*)(ws + OFF_POSS);
    float* G = (float*)(ws + OFF_G);
    double* oacc = (double*)(ws + OFF_OACC);
    int* done = (int*)(ws + OFF_DONE);
    float* cs_part = (float*)(ws + OFF_CSP);
    int* cc_part = (int*)(ws + OFF_CCP);
    float* W = (float*)(ws + OFF_W);

    scl_stage1<<<4169, 256, 0, stream>>>(rep, sl, labels, (uint32_t*)rnf8,
                                         cs_part, cc_part, ws + OFF_DENOM);
    scl_main<<<1056, 256, 0, stream>>>(rnf8, sl, labels, cs_part, cc_part, pwp,
                                       denom, posS, G, W);
    scl_finalize<<<9, 256, 0, stream>>>(denom, posS, W, G, pwp, oacc, done,
                                        (float*)d_out);
}